// Round 1
// baseline (138.289 us; speedup 1.0000x reference)
//
#include <hip/hip_runtime.h>

#define N_NODES   10000
#define DEG       32
#define N_EDGES   (N_NODES * DEG)
#define IN_FEATS  256
#define HEADS     8
#define OUT_FEATS 64
#define HD        (HEADS * OUT_FEATS)   // 512
#define NEG_SLOPE 0.2f

// ---------------------------------------------------------------------------
// Kernel A: ft = feat @ W   (M=10000, K=256, N=512) fp32, 64x64x16 LDS tile,
// 4x4 microtile per thread, 256 threads/block.
// ---------------------------------------------------------------------------
__global__ __launch_bounds__(256) void gemm_ft(const float* __restrict__ A,
                                               const float* __restrict__ B,
                                               float* __restrict__ C) {
    constexpr int BM = 64, BN = 64, BK = 16;
    __shared__ alignas(16) float As[BK][BM];
    __shared__ alignas(16) float Bs[BK][BN];

    const int t  = threadIdx.x;
    const int m0 = blockIdx.x * BM;
    const int n0 = blockIdx.y * BN;
    const int ty = t >> 4;   // 0..15
    const int tx = t & 15;   // 0..15

    // A-tile load mapping: 64 rows x 16 cols, one float4 per thread
    const int lr = t >> 2;   // tile row 0..63
    const int lq = t & 3;    // k-quarter 0..3
    // B-tile load mapping: 16 rows x 64 cols, one float4 per thread
    const int br = t >> 4;   // tile row 0..15
    const int bq = t & 15;   // col-quarter 0..15

    float acc[4][4] = {};

    for (int k0 = 0; k0 < IN_FEATS; k0 += BK) {
        float4 av = make_float4(0.f, 0.f, 0.f, 0.f);
        const int gm = m0 + lr;
        if (gm < N_NODES)
            av = *reinterpret_cast<const float4*>(&A[(size_t)gm * IN_FEATS + k0 + lq * 4]);
        As[lq * 4 + 0][lr] = av.x;
        As[lq * 4 + 1][lr] = av.y;
        As[lq * 4 + 2][lr] = av.z;
        As[lq * 4 + 3][lr] = av.w;

        const float4 bv = *reinterpret_cast<const float4*>(&B[(size_t)(k0 + br) * HD + n0 + bq * 4]);
        *reinterpret_cast<float4*>(&Bs[br][bq * 4]) = bv;

        __syncthreads();

        #pragma unroll
        for (int kk = 0; kk < BK; ++kk) {
            const float4 a4 = *reinterpret_cast<const float4*>(&As[kk][ty * 4]);
            const float4 b4 = *reinterpret_cast<const float4*>(&Bs[kk][tx * 4]);
            const float a[4] = {a4.x, a4.y, a4.z, a4.w};
            const float b[4] = {b4.x, b4.y, b4.z, b4.w};
            #pragma unroll
            for (int i = 0; i < 4; ++i)
                #pragma unroll
                for (int j = 0; j < 4; ++j)
                    acc[i][j] = fmaf(a[i], b[j], acc[i][j]);
        }
        __syncthreads();
    }

    #pragma unroll
    for (int i = 0; i < 4; ++i) {
        const int gm = m0 + ty * 4 + i;
        if (gm >= N_NODES) continue;
        float4 v = make_float4(acc[i][0], acc[i][1], acc[i][2], acc[i][3]);
        *reinterpret_cast<float4*>(&C[(size_t)gm * HD + n0 + tx * 4]) = v;
    }
}

// ---------------------------------------------------------------------------
// Kernel B: el[n,h] = dot(ft[n,h,:], attn_l[h,:]);  er likewise.
// One wave per (n,h); lane = d.
// ---------------------------------------------------------------------------
__global__ __launch_bounds__(256) void logits_kernel(const float* __restrict__ ft,
                                                     const float* __restrict__ attn_l,
                                                     const float* __restrict__ attn_r,
                                                     float* __restrict__ el,
                                                     float* __restrict__ er) {
    const int wave = threadIdx.x >> 6;
    const int lane = threadIdx.x & 63;
    const int idx  = blockIdx.x * 4 + wave;   // n*HEADS + h
    if (idx >= N_NODES * HEADS) return;
    const int n = idx >> 3;
    const int h = idx & 7;

    const float v  = ft[(size_t)n * HD + h * OUT_FEATS + lane];
    float vl = v * attn_l[h * OUT_FEATS + lane];
    float vr = v * attn_r[h * OUT_FEATS + lane];
    #pragma unroll
    for (int m = 32; m; m >>= 1) {
        vl += __shfl_xor(vl, m, 64);
        vr += __shfl_xor(vr, m, 64);
    }
    if (lane == 0) {
        el[idx] = vl;
        er[idx] = vr;
    }
}

// ---------------------------------------------------------------------------
// Kernel C: per destination node: edge logits -> LeakyReLU -> softmax over its
// 32 contiguous edges -> write a -> weighted aggregation of ft[src].
// Block = 256 threads = 4 waves; softmax groups: h = t>>5 (32 lanes each).
// ---------------------------------------------------------------------------
__global__ __launch_bounds__(256) void edge_agg(const float* __restrict__ ft,
                                                const float* __restrict__ el,
                                                const float* __restrict__ er,
                                                const int* __restrict__ src,
                                                float* __restrict__ rst,
                                                float* __restrict__ out_a) {
    __shared__ int   s_src[DEG];
    __shared__ float s_a[DEG][HEADS];

    const int n = blockIdx.x;
    const int t = threadIdx.x;

    if (t < DEG) s_src[t] = src[n * DEG + t];
    __syncthreads();

    // --- softmax over the 32 edges, per head ---
    const int h = t >> 5;   // 0..7
    const int j = t & 31;   // 0..31
    const int s = s_src[j];
    float e = el[s * HEADS + h] + er[n * HEADS + h];
    e = (e > 0.f) ? e : NEG_SLOPE * e;

    float m = e;
    #pragma unroll
    for (int msk = 16; msk; msk >>= 1) m = fmaxf(m, __shfl_xor(m, msk, 64));
    const float ex = __expf(e - m);
    float sum = ex;
    #pragma unroll
    for (int msk = 16; msk; msk >>= 1) sum += __shfl_xor(sum, msk, 64);
    const float a = ex / sum;
    s_a[j][h] = a;
    __syncthreads();

    // --- write attention output coalesced: out_a[(n*DEG + j)*HEADS + h] ---
    out_a[(size_t)n * (DEG * HEADS) + t] = s_a[t >> 3][t & 7];

    // --- weighted aggregation: rst[n, c] = sum_j a[j, c/64] * ft[src_j, c] ---
    const int c0 = t;
    const int c1 = t + 256;
    const int h0 = c0 >> 6;
    const int h1 = c1 >> 6;
    float acc0 = 0.f, acc1 = 0.f;
    #pragma unroll 8
    for (int jj = 0; jj < DEG; ++jj) {
        const float* row = ft + (size_t)s_src[jj] * HD;
        const float w0 = s_a[jj][h0];
        const float w1 = s_a[jj][h1];
        acc0 = fmaf(w0, row[c0], acc0);
        acc1 = fmaf(w1, row[c1], acc1);
    }
    rst[(size_t)n * HD + c0] = acc0;
    rst[(size_t)n * HD + c1] = acc1;
}

// ---------------------------------------------------------------------------
extern "C" void kernel_launch(void* const* d_in, const int* in_sizes, int n_in,
                              void* d_out, int out_size, void* d_ws, size_t ws_size,
                              hipStream_t stream) {
    const float* feat   = (const float*)d_in[0];
    const float* W      = (const float*)d_in[1];
    const float* attn_l = (const float*)d_in[2];
    const float* attn_r = (const float*)d_in[3];
    const int*   src    = (const int*)d_in[4];
    // d_in[5] = dst (structure known: repeat(arange(N), DEG))

    float* out_rst = (float*)d_out;                       // [N, H, D]
    float* out_a   = out_rst + (size_t)N_NODES * HD;      // [E, H]

    float* ft = (float*)d_ws;                             // [N, HD]
    float* el = ft + (size_t)N_NODES * HD;                // [N, H]
    float* er = el + (size_t)N_NODES * HEADS;             // [N, H]

    // 1) projection
    dim3 gGemm((N_NODES + 63) / 64, HD / 64);
    gemm_ft<<<gGemm, 256, 0, stream>>>(feat, W, ft);

    // 2) per-node logits
    logits_kernel<<<(N_NODES * HEADS + 3) / 4, 256, 0, stream>>>(ft, attn_l, attn_r, el, er);

    // 3) edge softmax + aggregation
    edge_agg<<<N_NODES, 256, 0, stream>>>(ft, el, er, src, out_rst, out_a);
}

// Round 2
// 71.982 us; speedup vs baseline: 1.9212x; 1.9212x over previous
//
#include <hip/hip_runtime.h>

#define N_NODES   10000
#define M_PAD     10112          // 79 * 128
#define DEG       32
#define IN_FEATS  256
#define HEADS     8
#define OUT_FEATS 64
#define HD        512
#define NEG_SLOPE 0.2f

typedef short bf16x8 __attribute__((ext_vector_type(8)));
typedef float f32x4  __attribute__((ext_vector_type(4)));

__device__ __forceinline__ ushort f2bf(float x) {
    union { float f; unsigned u; } c; c.f = x;
    unsigned r = (c.u + 0x7fffu + ((c.u >> 16) & 1u)) >> 16;   // RNE
    return (ushort)r;
}
__device__ __forceinline__ float bfbits2f(unsigned hi_bits) {  // bits already in [31:16]
    union { unsigned u; float f; } c; c.u = hi_bits;
    return c.f;
}

// ---------------------------------------------------------------------------
// feat fp32 -> bf16   (10000*256 = 640000 float4s)
// ---------------------------------------------------------------------------
__global__ __launch_bounds__(256) void convert_feat(const float* __restrict__ f,
                                                    ushort* __restrict__ fb) {
    const int i = blockIdx.x * 256 + threadIdx.x;   // float4 index
    const float4 v = reinterpret_cast<const float4*>(f)[i];
    ushort4 o;
    o.x = f2bf(v.x); o.y = f2bf(v.y); o.z = f2bf(v.z); o.w = f2bf(v.w);
    reinterpret_cast<ushort4*>(fb)[i] = o;
}

// ---------------------------------------------------------------------------
// W [K=256][N=512] fp32 -> W_bt [N=512][K=256] bf16 (transpose via LDS tile)
// grid (4, 8): 64x64 tiles
// ---------------------------------------------------------------------------
__global__ __launch_bounds__(256) void convert_W(const float* __restrict__ W,
                                                 ushort* __restrict__ Bt) {
    __shared__ ushort s[64][72];     // [n][k], padded
    const int kb = blockIdx.x * 64;
    const int nb = blockIdx.y * 64;
    const int t  = threadIdx.x;
    #pragma unroll
    for (int rep = 0; rep < 4; ++rep) {
        const int kk = rep * 16 + (t >> 4);
        const int nn = (t & 15) * 4;
        const float4 v = *reinterpret_cast<const float4*>(&W[(size_t)(kb + kk) * HD + nb + nn]);
        s[nn + 0][kk] = f2bf(v.x);
        s[nn + 1][kk] = f2bf(v.y);
        s[nn + 2][kk] = f2bf(v.z);
        s[nn + 3][kk] = f2bf(v.w);
    }
    __syncthreads();
    const int nn = t >> 2;           // 0..63
    const int k0 = (t & 3) * 16;     // 0,16,32,48
    #pragma unroll
    for (int c = 0; c < 2; ++c) {
        *reinterpret_cast<uint4*>(&Bt[(size_t)(nb + nn) * IN_FEATS + kb + k0 + c * 8]) =
            *reinterpret_cast<const uint4*>(&s[nn][k0 + c * 8]);
    }
}

// ---------------------------------------------------------------------------
// ft_bf16 = feat_bf @ W_bt^T : M=10112(pad), N=512, K=256
// 128x128 tile, BK=32, 4 waves (2x2 of 64x64), mfma_f32_16x16x32_bf16.
// LDS: [row][32k] bf16 with 16B-chunk XOR swizzle q ^= (row>>1)&3 on both
// write and read sides (conflict-free ds_write_b128 / ds_read_b128).
// ---------------------------------------------------------------------------
__global__ __launch_bounds__(256) void gemm_mfma(const ushort* __restrict__ A,
                                                 const ushort* __restrict__ Bt,
                                                 ushort* __restrict__ C) {
    __shared__ ushort As[128 * 32];
    __shared__ ushort Bs[128 * 32];
    const int t    = threadIdx.x;
    const int lane = t & 63;
    const int m0   = blockIdx.x * 128;
    const int n0   = blockIdx.y * 128;
    const int wave = t >> 6;
    const int wr   = (wave >> 1) * 64;
    const int wc   = (wave & 1) * 64;

    // staging: each thread stages two 16B chunks per tile per operand
    const int srow0 = t >> 2;          // 0..63
    const int srow1 = 64 + (t >> 2);   // 64..127
    const int sq    = t & 3;
    const int sq0   = sq ^ ((srow0 >> 1) & 3);
    const int sq1   = sq ^ ((srow1 >> 1) & 3);

    uint4 ra0, ra1, rb0, rb1;
#define LOADREGS(K0)                                                                   \
    do {                                                                               \
        ra0 = *reinterpret_cast<const uint4*>(A  + (size_t)(m0 + srow0) * IN_FEATS + (K0) + sq * 8); \
        ra1 = *reinterpret_cast<const uint4*>(A  + (size_t)(m0 + srow1) * IN_FEATS + (K0) + sq * 8); \
        rb0 = *reinterpret_cast<const uint4*>(Bt + (size_t)(n0 + srow0) * IN_FEATS + (K0) + sq * 8); \
        rb1 = *reinterpret_cast<const uint4*>(Bt + (size_t)(n0 + srow1) * IN_FEATS + (K0) + sq * 8); \
    } while (0)

    f32x4 acc[4][4];
    #pragma unroll
    for (int i = 0; i < 4; ++i)
        #pragma unroll
        for (int j = 0; j < 4; ++j)
            acc[i][j] = (f32x4){0.f, 0.f, 0.f, 0.f};

    // read-side swizzled 16B-chunk offset (elements): same for every fragment
    const int rqoff = (((lane >> 4) ^ (((lane & 15) >> 1) & 3)) * 8);
    const int rl    = lane & 15;

    LOADREGS(0);
    for (int k0 = 0; k0 < IN_FEATS; k0 += 32) {
        __syncthreads();
        *reinterpret_cast<uint4*>(As + srow0 * 32 + sq0 * 8) = ra0;
        *reinterpret_cast<uint4*>(As + srow1 * 32 + sq1 * 8) = ra1;
        *reinterpret_cast<uint4*>(Bs + srow0 * 32 + sq0 * 8) = rb0;
        *reinterpret_cast<uint4*>(Bs + srow1 * 32 + sq1 * 8) = rb1;
        __syncthreads();
        if (k0 + 32 < IN_FEATS) LOADREGS(k0 + 32);

        bf16x8 af[4], bfr[4];
        #pragma unroll
        for (int i = 0; i < 4; ++i)
            af[i] = *reinterpret_cast<const bf16x8*>(As + (wr + i * 16 + rl) * 32 + rqoff);
        #pragma unroll
        for (int j = 0; j < 4; ++j)
            bfr[j] = *reinterpret_cast<const bf16x8*>(Bs + (wc + j * 16 + rl) * 32 + rqoff);
        #pragma unroll
        for (int i = 0; i < 4; ++i)
            #pragma unroll
            for (int j = 0; j < 4; ++j)
                acc[i][j] = __builtin_amdgcn_mfma_f32_16x16x32_bf16(af[i], bfr[j], acc[i][j], 0, 0, 0);
    }
#undef LOADREGS

    // epilogue: D lane l reg r -> row=(l>>4)*4+r, col=l&15
    const int rbase = (lane >> 4) * 4;
    #pragma unroll
    for (int i = 0; i < 4; ++i) {
        #pragma unroll
        for (int r = 0; r < 4; ++r) {
            const int gm = m0 + wr + i * 16 + rbase + r;
            ushort* dst = C + (size_t)gm * HD + n0 + wc + rl;
            #pragma unroll
            for (int j = 0; j < 4; ++j)
                dst[j * 16] = f2bf(acc[i][j][r]);
        }
    }
}

// ---------------------------------------------------------------------------
// el[n,h] = dot(ft[n,h,:], attn_l[h,:]);  er likewise. One wave per (n,h).
// ---------------------------------------------------------------------------
__global__ __launch_bounds__(256) void logits_kernel(const ushort* __restrict__ ftb,
                                                     const float* __restrict__ attn_l,
                                                     const float* __restrict__ attn_r,
                                                     float* __restrict__ el,
                                                     float* __restrict__ er) {
    const int wave = threadIdx.x >> 6;
    const int lane = threadIdx.x & 63;
    const int idx  = blockIdx.x * 4 + wave;   // n*HEADS + h
    if (idx >= N_NODES * HEADS) return;
    const int n = idx >> 3;
    const int h = idx & 7;

    const float v = bfbits2f((unsigned)ftb[(size_t)n * HD + h * OUT_FEATS + lane] << 16);
    float vl = v * attn_l[h * OUT_FEATS + lane];
    float vr = v * attn_r[h * OUT_FEATS + lane];
    #pragma unroll
    for (int m = 32; m; m >>= 1) {
        vl += __shfl_xor(vl, m, 64);
        vr += __shfl_xor(vr, m, 64);
    }
    if (lane == 0) {
        el[idx] = vl;
        er[idx] = vr;
    }
}

// ---------------------------------------------------------------------------
// Per destination node: edge softmax (32 contiguous edges) + aggregation.
// Gather from bf16 ft: each thread owns cols 2t,2t+1 (one dword per row).
// ---------------------------------------------------------------------------
__global__ __launch_bounds__(256) void edge_agg(const uint* __restrict__ ftb,
                                                const float* __restrict__ el,
                                                const float* __restrict__ er,
                                                const int* __restrict__ src,
                                                float* __restrict__ rst,
                                                float* __restrict__ out_a) {
    __shared__ int   s_src[DEG];
    __shared__ float s_a[DEG][HEADS];

    const int n = blockIdx.x;
    const int t = threadIdx.x;

    if (t < DEG) s_src[t] = src[n * DEG + t];
    __syncthreads();

    // softmax: h = t>>5 (8 groups of 32 lanes), j = t&31 (edge)
    const int h = t >> 5;
    const int j = t & 31;
    const int s = s_src[j];
    float e = el[s * HEADS + h] + er[n * HEADS + h];
    e = (e > 0.f) ? e : NEG_SLOPE * e;

    float m = e;
    #pragma unroll
    for (int msk = 16; msk; msk >>= 1) m = fmaxf(m, __shfl_xor(m, msk, 64));
    const float ex = __expf(e - m);
    float sum = ex;
    #pragma unroll
    for (int msk = 16; msk; msk >>= 1) sum += __shfl_xor(sum, msk, 64);
    s_a[j][h] = ex / sum;
    __syncthreads();

    // a output: [E, H, 1] -> out_a[n*256 + j*8 + h]
    out_a[(size_t)n * 256 + t] = s_a[t >> 3][t & 7];

    // aggregation: thread owns cols 2t, 2t+1 (same head h = t>>5)
    float a0 = 0.f, a1 = 0.f;
    #pragma unroll
    for (int jj = 0; jj < DEG; ++jj) {
        const uint  u = ftb[(size_t)s_src[jj] * 256 + t];
        const float w = s_a[jj][h];
        a0 = fmaf(w, bfbits2f(u << 16), a0);
        a1 = fmaf(w, bfbits2f(u & 0xffff0000u), a1);
    }
    *reinterpret_cast<float2*>(&rst[(size_t)n * HD + 2 * t]) = make_float2(a0, a1);
}

// ---------------------------------------------------------------------------
extern "C" void kernel_launch(void* const* d_in, const int* in_sizes, int n_in,
                              void* d_out, int out_size, void* d_ws, size_t ws_size,
                              hipStream_t stream) {
    const float* feat   = (const float*)d_in[0];
    const float* W      = (const float*)d_in[1];
    const float* attn_l = (const float*)d_in[2];
    const float* attn_r = (const float*)d_in[3];
    const int*   src    = (const int*)d_in[4];

    float* out_rst = (float*)d_out;                     // [N, H, D]
    float* out_a   = out_rst + (size_t)N_NODES * HD;    // [E, H, 1]

    char* w = (char*)d_ws;
    ushort* feat_bf = (ushort*)w;  w += (size_t)M_PAD * IN_FEATS * 2;   // 5.18 MB
    ushort* W_bt    = (ushort*)w;  w += (size_t)HD * IN_FEATS * 2;      // 0.26 MB
    ushort* ftb     = (ushort*)w;  w += (size_t)M_PAD * HD * 2;         // 10.35 MB
    float*  el      = (float*)w;   w += (size_t)N_NODES * HEADS * 4;
    float*  er      = (float*)w;

    convert_feat<<<(N_NODES * IN_FEATS / 4) / 256, 256, 0, stream>>>(feat, feat_bf);
    convert_W<<<dim3(IN_FEATS / 64, HD / 64), 256, 0, stream>>>(W, W_bt);
    gemm_mfma<<<dim3(M_PAD / 128, HD / 128), 256, 0, stream>>>(feat_bf, W_bt, ftb);
    logits_kernel<<<(N_NODES * HEADS + 3) / 4, 256, 0, stream>>>(ftb, attn_l, attn_r, el, er);
    edge_agg<<<N_NODES, 256, 0, stream>>>((const uint*)ftb, el, er, src, out_rst, out_a);
}